// Round 6
// baseline (104.254 us; speedup 1.0000x reference)
//
#include <hip/hip_runtime.h>

#define N_PARTS 62
#define M_SAMP  512
#define D_DIM   256
#define MARGIN  0.2f

typedef unsigned short ushort_t;
typedef __attribute__((ext_vector_type(8))) short bf16x8;   // 8 bf16 = 4 VGPRs
typedef __attribute__((ext_vector_type(4))) float f32x4;

typedef const __attribute__((address_space(1))) unsigned gu32;
typedef __attribute__((address_space(3))) unsigned lu32;

__device__ __forceinline__ ushort_t bf16_rne(float f) {
    unsigned u = __float_as_uint(f);
    unsigned r = u + 0x7fffu + ((u >> 16) & 1u);
    return (ushort_t)(r >> 16);
}

__device__ __forceinline__ float bf16_val(float f) {
    return __uint_as_float((unsigned)bf16_rne(f) << 16);
}

// Build a bf16x8 MFMA fragment from two fp32 quads (RNE, same bits as the
// verified prep path).
__device__ __forceinline__ bf16x8 cvt_frag(f32x4 a0, f32x4 a1) {
    union { bf16x8 v; unsigned u[4]; } r;
    r.u[0] = (unsigned)bf16_rne(a0.x) | ((unsigned)bf16_rne(a0.y) << 16);
    r.u[1] = (unsigned)bf16_rne(a0.z) | ((unsigned)bf16_rne(a0.w) << 16);
    r.u[2] = (unsigned)bf16_rne(a1.x) | ((unsigned)bf16_rne(a1.y) << 16);
    r.u[3] = (unsigned)bf16_rne(a1.z) | ((unsigned)bf16_rne(a1.w) << 16);
    return r.v;
}

__global__ void zero_out_kernel(float* __restrict__ out) {
    if (threadIdx.x < 2 * N_PARTS) out[threadIdx.x] = 0.0f;
}

// R5 post-mortem: two-kernel pipeline pays a 16 MB HBM write + 16 MB read
// + a launch + full drain for the bf16 intermediate; measured kernel-side
// time ~31 us vs ~12 us roofline. This kernel fuses everything:
//  - fp32 staged chunk-wise (32 cols) straight into LDS via global_load_lds
//    (no VGPR round-trip -> fits the 128-VGPR pin from R1-R3), double
//    buffered, loads for chunk c+1 in flight across chunk c's MFMAs.
//  - slot-XOR swizzle (slot ^= row&7) applied on the GLOBAL source address
//    (LDS dest of global_load_lds must stay linear); every ds_read_b128
//    (fragments + sq pass) then hits 8 accesses/bank = the b128 minimum.
//  - bf16 RNE conversion at fragment build; per-row sum-of-squares of the
//    ROUNDED values accumulated per-thread (thread t owns row t).
//  - 64x64 per-wave tile (acc[4][4] = 64 regs): loop demand ~120 < 128.
// Grid 8x64 (XCD affinity id%8==n%8), 248 active blocks, 1 block/CU
// (LDS 136 KB), one-shot residency.
__global__ __launch_bounds__(512)
__attribute__((amdgpu_waves_per_eu(2, 4)))
void fused_kernel(const float* __restrict__ feat, float* __restrict__ out) {
    const int id = blockIdx.x;
    const int n  = id & 63;          // part
    const int ct = id >> 6;          // col-slab (64 cols, 0..7)
    if (n >= N_PARTS) return;
    const int tid  = threadIdx.x;
    const int wave = tid >> 6, lane = tid & 63;

    __shared__ float tile[2][512 * 32];   // 2 x 64 KB fp32, slot-swizzled
    __shared__ float sqA[M_SAMP];         // per-row sum-of-squares (rounded)
    __shared__ float mrg[8][64][3];       // [wave][slab-local col][hp,hn,ds]

    const float* fpart = feat + (size_t)n * (M_SAMP * D_DIM);

    // Staging: 1 KB slot s covers rows s*8..s*8+7 (128 B each, linear LDS).
    // Lane l of an issue -> row s*8 + (l>>3), LDS 16B-slot l&7. Content must
    // be global float4 (l&7) ^ (row&7) = (l&7) ^ (l>>3) of the chunk.
    const int srow = lane >> 3;                     // 0..7
    const int scol = (lane & 7) ^ srow;             // pre-swizzled float4 idx
    const float* gbase = fpart + (size_t)srow * D_DIM + (size_t)scol * 4;

    // ---- prologue: stage chunk 0 into buf 0 (8 issues/wave, 64 KB total)
    #pragma unroll
    for (int j = 0; j < 8; ++j) {
        const int s = wave + 8 * j;
        __builtin_amdgcn_global_load_lds(
            (gu32*)(gbase + (size_t)s * 8 * D_DIM),
            (lu32*)(uintptr_t)&tile[0][s * 256], 16, 0, 0);
    }
    __syncthreads();

    // ---- per-lane fragment addressing (floats). For 16-aligned row groups,
    // row&7 == lane&7, so the swizzled slots are lane-constant:
    const int fr  = lane & 15;            // row within group
    const int q   = lane >> 4;            // k-quad
    const int sl1 = (2 * q) ^ (fr & 7);   // swizzled slot of k=8q..8q+3
    const int sl2 = (2 * q + 1) ^ (fr & 7);
    const int aoff = (wave * 64 + fr) * 32;   // A rows w*64..
    const int boff = (ct * 64 + fr) * 32;     // B rows = slab cols
    const int soff = tid * 32;                // sq row (thread owns row tid)
    const int sx   = tid & 7;

    f32x4 acc[4][4] = {};
    float sqp = 0.f;

    #pragma unroll
    for (int c = 0; c < 8; ++c) {
        const float* tb = tile[c & 1];
        // issue next-chunk staging first: loads fly under this chunk's work
        if (c < 7) {
            float* tn = tile[(c + 1) & 1];
            #pragma unroll
            for (int j = 0; j < 8; ++j) {
                const int s = wave + 8 * j;
                __builtin_amdgcn_global_load_lds(
                    (gu32*)(gbase + (size_t)s * 8 * D_DIM + (c + 1) * 32),
                    (lu32*)(uintptr_t)&tn[s * 256], 16, 0, 0);
            }
        }
        // sum-of-squares pass: thread reads its row's 8 swizzled quads
        #pragma unroll
        for (int s = 0; s < 8; ++s) {
            const f32x4 v = *(const f32x4*)&tb[soff + ((s ^ sx) << 2)];
            const float a = bf16_val(v.x), b = bf16_val(v.y),
                        e = bf16_val(v.z), d = bf16_val(v.w);
            sqp += a * a + b * b + e * e + d * d;
        }
        // A fragments (convert at read)
        bf16x8 af[4];
        #pragma unroll
        for (int mi = 0; mi < 4; ++mi)
            af[mi] = cvt_frag(*(const f32x4*)&tb[aoff + mi * 512 + sl1 * 4],
                              *(const f32x4*)&tb[aoff + mi * 512 + sl2 * 4]);
        // stream B fragments, one live at a time
        #pragma unroll
        for (int ni = 0; ni < 4; ++ni) {
            const bf16x8 bfv = cvt_frag(*(const f32x4*)&tb[boff + ni * 512 + sl1 * 4],
                                        *(const f32x4*)&tb[boff + ni * 512 + sl2 * 4]);
            #pragma unroll
            for (int mi = 0; mi < 4; ++mi)
                acc[mi][ni] = __builtin_amdgcn_mfma_f32_16x16x32_bf16(
                    af[mi], bfv, acc[mi][ni], 0, 0, 0);
        }
        __syncthreads();   // drains vmcnt: next chunk's staging complete
    }

    sqA[tid] = sqp;
    __syncthreads();

    // ---- epilogue (verified R12 structure; SQ from LDS). C/D layout:
    // col = lane&15, row = (lane>>4)*4 + reg.
    float sqr[4][4];
    #pragma unroll
    for (int mi = 0; mi < 4; ++mi)
        #pragma unroll
        for (int p = 0; p < 4; ++p)
            sqr[mi][p] = sqA[wave * 64 + mi * 16 + (lane >> 4) * 4 + p];

    #pragma unroll
    for (int ni = 0; ni < 4; ++ni) {
        const int C = ct * 64 + ni * 16 + (lane & 15);     // part-local col
        const float sc = sqA[C];
        const int Cg = C >> 3;                             // label = m>>3
        float ds = 0.f, hp = 0.f, hn = 1e30f;
        #pragma unroll
        for (int mi = 0; mi < 4; ++mi) {
            #pragma unroll
            for (int p = 0; p < 4; ++p) {
                const int R = wave * 64 + mi * 16 + (lane >> 4) * 4 + p;
                const float d2 = sqr[mi][p] + sc - 2.f * acc[mi][ni][p];
                const float d  = __builtin_amdgcn_sqrtf(fmaxf(d2, 0.f));
                ds += d;
                if ((R >> 3) == Cg) hp = fmaxf(hp, d);
                else                hn = fminf(hn, d);
            }
        }
        // combine the 4 quads (same col, disjoint row subsets)
        #pragma unroll
        for (int off = 16; off < 64; off <<= 1) {
            ds += __shfl_xor(ds, off);
            hp = fmaxf(hp, __shfl_xor(hp, off));
            hn = fminf(hn, __shfl_xor(hn, off));
        }
        if (lane < 16) {
            mrg[wave][ni * 16 + lane][0] = hp;
            mrg[wave][ni * 16 + lane][1] = hn;
            mrg[wave][ni * 16 + lane][2] = ds;
        }
    }
    __syncthreads();
    if (tid < 64) {   // col tid of the slab: merge 8 row-strips, then reduce
        float hp = 0.f, hn = 1e30f, bd = 0.f;
        #pragma unroll
        for (int w = 0; w < 8; ++w) {
            hp = fmaxf(hp, mrg[w][tid][0]);
            hn = fminf(hn, mrg[w][tid][1]);
            bd += mrg[w][tid][2];
        }
        float bl = fmaxf(MARGIN + hp - hn, 0.f);
        #pragma unroll
        for (int off = 32; off > 0; off >>= 1) {
            bl += __shfl_xor(bl, off);
            bd += __shfl_xor(bd, off);
        }
        if (tid == 0) {
            atomicAdd(&out[n],           bl * (1.0f / 512.0f));
            atomicAdd(&out[N_PARTS + n], bd * (1.0f / (512.0f * 512.0f)));
        }
    }
}

extern "C" void kernel_launch(void* const* d_in, const int* in_sizes, int n_in,
                              void* d_out, int out_size, void* d_ws, size_t ws_size,
                              hipStream_t stream) {
    const float* feat = (const float*)d_in[0];    // [62, 512, 256] fp32
    float* out = (float*)d_out;                   // [124]
    (void)d_ws; (void)ws_size;                    // no workspace needed

    zero_out_kernel<<<dim3(1), 128, 0, stream>>>(out);
    fused_kernel<<<dim3(8 * 64), 512, 0, stream>>>(feat, out);
}